// Round 1
// baseline (699.050 us; speedup 1.0000x reference)
//
#include <hip/hip_runtime.h>
#include <hip/hip_bf16.h>

// Sizes
#define BATCH 512
#define HID   4096
#define NC    32
#define CD    64
#define CB    1024
#define NCD   2048   // NC*CD

// ---------------------------------------------------------------------------
// GEMM (NT): C[m][n] = bias[n] + sum_k A[m][k] * B[n][k]
// A: [M][K] row-major, B: [N][K] row-major. 64x64 tile, 256 thr, 4x4/thread.
// ---------------------------------------------------------------------------
__global__ __launch_bounds__(256) void gemm_nt_bias(
    const float* __restrict__ A, const float* __restrict__ B,
    const float* __restrict__ bias, float* __restrict__ C,
    int M, int N, int K) {
  __shared__ float As[64][68];  // transposed: As[k][m]
  __shared__ float Bs[64][68];  // transposed: Bs[k][n]
  const int t  = threadIdx.x;
  const int tx = t & 15, ty = t >> 4;
  const int bm = blockIdx.x * 64, bn = blockIdx.y * 64;
  const float* Ab = A + (size_t)bm * K;
  const float* Bb = B + (size_t)bn * K;
  float acc[4][4] = {};
  for (int k0 = 0; k0 < K; k0 += 64) {
#pragma unroll
    for (int p = 0; p < 4; ++p) {
      int row = (t >> 4) + p * 16;   // 0..63
      int col = (t & 15) * 4;        // 0..60
      float4 av = *(const float4*)&Ab[(size_t)row * K + k0 + col];
      float4 bv = *(const float4*)&Bb[(size_t)row * K + k0 + col];
      As[col + 0][row] = av.x; As[col + 1][row] = av.y;
      As[col + 2][row] = av.z; As[col + 3][row] = av.w;
      Bs[col + 0][row] = bv.x; Bs[col + 1][row] = bv.y;
      Bs[col + 2][row] = bv.z; Bs[col + 3][row] = bv.w;
    }
    __syncthreads();
#pragma unroll 8
    for (int kk = 0; kk < 64; ++kk) {
      float4 a4 = *(const float4*)&As[kk][ty * 4];
      float4 b4 = *(const float4*)&Bs[kk][tx * 4];
      float a_[4] = {a4.x, a4.y, a4.z, a4.w};
      float b_[4] = {b4.x, b4.y, b4.z, b4.w};
#pragma unroll
      for (int i = 0; i < 4; ++i)
#pragma unroll
        for (int j = 0; j < 4; ++j)
          acc[i][j] += a_[i] * b_[j];
    }
    __syncthreads();
  }
  float4 bv = *(const float4*)&bias[bn + tx * 4];
  float bb[4] = {bv.x, bv.y, bv.z, bv.w};
#pragma unroll
  for (int i = 0; i < 4; ++i) {
    float4 o;
    o.x = acc[i][0] + bb[0];
    o.y = acc[i][1] + bb[1];
    o.z = acc[i][2] + bb[2];
    o.w = acc[i][3] + bb[3];
    *(float4*)&C[(size_t)(bm + ty * 4 + i) * N + bn + tx * 4] = o;
  }
}

// ---------------------------------------------------------------------------
// Per-sample: build 32x1024 cost matrix (Euclidean dist e->codebook) in LDS,
// run Jonker-Volgenant shortest augmenting path (f64 duals, matching the
// reference's float64 internals), emit indices (as float) and q gather.
// One block = one sample. 256 threads. ~156 KiB dynamic LDS.
// ---------------------------------------------------------------------------
#define SMEM_BYTES 156544

__global__ __launch_bounds__(256) void k_assign(
    const float* __restrict__ e_glob, const float* __restrict__ codebook,
    float* __restrict__ q_out, float* __restrict__ idx_out) {
  extern __shared__ char smem_raw[];
  float* cost = (float*)smem_raw;                     // [32][1024] f32
  char* uni = smem_raw + 131072;                      // 25088-byte union
  // fill-phase view
  float* ecache = (float*)uni;                        // [32][64]
  float* cbt    = (float*)(uni + 8192);               // [64][66]
  // hungarian-phase view
  double* v    = (double*)uni;                        // [1025]
  double* minv = (double*)(uni + 8200);               // [1025]
  double* u    = (double*)(uni + 16400);              // [33]
  unsigned short* way = (unsigned short*)(uni + 16664); // [1025]
  unsigned char* pm   = (unsigned char*)(uni + 18714);  // [1025]
  unsigned char* used = (unsigned char*)(uni + 19739);  // [1025]
  // tail
  float* enorm = (float*)(smem_raw + 156160);         // [32]
  int*   idxl  = (int*)(smem_raw + 156288);           // [32]
  double* redv = (double*)(smem_raw + 156416);        // [4]
  int*   redj  = (int*)(smem_raw + 156448);           // [4]
  double* sdelta = (double*)(smem_raw + 156464);
  int*   skcol = (int*)(smem_raw + 156472);
  int*   sdone = (int*)(smem_raw + 156476);

  const int t = threadIdx.x;
  const int s = blockIdx.x;

  // ---- Phase A: stage e[s] (32x64), compute row norms ----
  {
    const float4* src = (const float4*)(e_glob + (size_t)s * NCD);
    ((float4*)ecache)[t] = src[t];
    ((float4*)ecache)[t + 256] = src[t + 256];
  }
  __syncthreads();
  {
    int r = t >> 3, part = t & 7;
    float sum = 0.f;
#pragma unroll
    for (int i = 0; i < 8; ++i) {
      float e0 = ecache[r * 64 + part * 8 + i];
      sum += e0 * e0;
    }
#pragma unroll
    for (int off = 4; off > 0; off >>= 1) sum += __shfl_down(sum, off);
    if (part == 0) enorm[r] = sum;
  }
  // (visible after the first __syncthreads below)

  // ---- Phase B: fill cost matrix, 16 tiles of 64 columns ----
  for (int tt = 0; tt < 16; ++tt) {
#pragma unroll
    for (int p = 0; p < 4; ++p) {
      int row = (t >> 4) + p * 16;
      int col = (t & 15) * 4;
      float4 cv = *(const float4*)&codebook[(size_t)(tt * 64 + row) * 64 + col];
      cbt[row * 66 + col + 0] = cv.x; cbt[row * 66 + col + 1] = cv.y;
      cbt[row * 66 + col + 2] = cv.z; cbt[row * 66 + col + 3] = cv.w;
    }
    __syncthreads();
    int jl = t & 31;
    int r0 = (t >> 5) * 4;
    float cn0 = 0.f, cn1 = 0.f;
    float dot[4][2] = {};
    for (int kk = 0; kk < 64; kk += 2) {
      float2 c0 = *(const float2*)&cbt[jl * 66 + kk];
      float2 c1 = *(const float2*)&cbt[(jl + 32) * 66 + kk];
      cn0 += c0.x * c0.x + c0.y * c0.y;
      cn1 += c1.x * c1.x + c1.y * c1.y;
#pragma unroll
      for (int i = 0; i < 4; ++i) {
        float2 ev = *(const float2*)&ecache[(r0 + i) * 64 + kk];
        dot[i][0] += ev.x * c0.x + ev.y * c0.y;
        dot[i][1] += ev.x * c1.x + ev.y * c1.y;
      }
    }
#pragma unroll
    for (int i = 0; i < 4; ++i) {
      float d0 = enorm[r0 + i] + cn0 - 2.f * dot[i][0];
      float d1 = enorm[r0 + i] + cn1 - 2.f * dot[i][1];
      cost[(r0 + i) * 1024 + tt * 64 + jl]      = sqrtf(fmaxf(d0, 0.f));
      cost[(r0 + i) * 1024 + tt * 64 + jl + 32] = sqrtf(fmaxf(d1, 0.f));
    }
    __syncthreads();
  }

  // ---- Phase C: Jonker-Volgenant (port of reference _lsa_single) ----
  for (int jj = t; jj < 1025; jj += 256) { v[jj] = 0.0; pm[jj] = 0; }
  if (t < 33) u[t] = 0.0;
  __syncthreads();

  for (int i = 1; i <= NC; ++i) {
    for (int jj = t; jj < 1025; jj += 256) {
      minv[jj] = 1e300; way[jj] = 0; used[jj] = 0;
    }
    if (t == 0) { pm[0] = (unsigned char)i; used[0] = 1; }
    __syncthreads();
    int j0 = 0;
    for (int guard = 0; guard < 1025; ++guard) {
      int i0 = pm[j0];
      double ui0 = u[i0];
      double bestv = 1e301; int bestj = 1 << 20;
#pragma unroll
      for (int rep = 0; rep < 4; ++rep) {
        int j = 1 + t + rep * 256;
        if (!used[j]) {
          double cur = (double)cost[(i0 - 1) * 1024 + (j - 1)] - ui0 - v[j];
          if (cur < minv[j]) { minv[j] = cur; way[j] = (unsigned short)j0; }
          double mv = minv[j];
          if (mv < bestv) { bestv = mv; bestj = j; }
        }
      }
#pragma unroll
      for (int off = 32; off > 0; off >>= 1) {
        double ov = __shfl_down(bestv, off);
        int oj = __shfl_down(bestj, off);
        if (ov < bestv || (ov == bestv && oj < bestj)) { bestv = ov; bestj = oj; }
      }
      if ((t & 63) == 0) { redv[t >> 6] = bestv; redj[t >> 6] = bestj; }
      __syncthreads();
      if (t == 0) {
        double dv = redv[0]; int dj = redj[0];
#pragma unroll
        for (int w = 1; w < 4; ++w)
          if (redv[w] < dv || (redv[w] == dv && redj[w] < dj)) { dv = redv[w]; dj = redj[w]; }
        *sdelta = dv; *skcol = dj;
        *sdone = (pm[dj] == 0) ? 1 : 0;
        used[dj] = 1;  // update phase treats j==k as still-free
      }
      __syncthreads();
      double delta = *sdelta; int k = *skcol; int done = *sdone;
#pragma unroll
      for (int rep = 0; rep < 4; ++rep) {
        int j = 1 + t + rep * 256;
        if (j != k && used[j]) { u[pm[j]] += delta; v[j] -= delta; }
        else { minv[j] -= delta; }
      }
      if (t == 0) { u[pm[0]] += delta; v[0] -= delta; }
      j0 = k;
      __syncthreads();
      if (done) break;
    }
    if (t == 0) {  // augment along the path
      int jj = j0;
      while (jj != 0) { int j1 = way[jj]; pm[jj] = pm[j1]; jj = j1; }
    }
    __syncthreads();
  }

  // ---- Phase D: emit indices + gather q ----
#pragma unroll
  for (int rep = 0; rep < 4; ++rep) {
    int j = 1 + t + rep * 256;
    int r = pm[j];
    if (r > 0) idxl[r - 1] = j - 1;
  }
  __syncthreads();
  if (t < NC) idx_out[(size_t)s * NC + t] = (float)idxl[t];
  {
    int r = t >> 3, c = (t & 7) * 8;
    int ci = idxl[r];
    float4 q0 = *(const float4*)&codebook[(size_t)ci * 64 + c];
    float4 q1 = *(const float4*)&codebook[(size_t)ci * 64 + c + 4];
    *(float4*)&q_out[(size_t)s * NCD + r * 64 + c]     = q0;
    *(float4*)&q_out[(size_t)s * NCD + r * 64 + c + 4] = q1;
  }
}

// ---------------------------------------------------------------------------
extern "C" void kernel_launch(void* const* d_in, const int* in_sizes, int n_in,
                              void* d_out, int out_size, void* d_ws, size_t ws_size,
                              hipStream_t stream) {
  (void)in_sizes; (void)n_in; (void)out_size; (void)d_ws; (void)ws_size;
  const float* x        = (const float*)d_in[0];
  const float* codebook = (const float*)d_in[1];
  const float* enc_w    = (const float*)d_in[2];
  const float* enc_b    = (const float*)d_in[3];
  const float* dec_w    = (const float*)d_in[4];
  const float* dec_b    = (const float*)d_in[5];

  float* out = (float*)d_out;
  float* r_out   = out;                       // [512][4096]
  float* q_out   = out + 2097152;             // [512][32][64]
  float* e_out   = out + 2097152 + 1048576;   // [512][32][64]
  float* idx_out = out + 2097152 + 2097152;   // [512][32] as float

  // K1: e = x @ enc_w.T + enc_b   (M=512, N=2048, K=4096)
  gemm_nt_bias<<<dim3(BATCH / 64, NCD / 64), 256, 0, stream>>>(
      x, enc_w, enc_b, e_out, BATCH, NCD, HID);

  // K2: distances + Hungarian + q gather (one block per sample)
  (void)hipFuncSetAttribute((const void*)k_assign,
                            hipFuncAttributeMaxDynamicSharedMemorySize,
                            SMEM_BYTES);
  k_assign<<<BATCH, 256, SMEM_BYTES, stream>>>(e_out, codebook, q_out, idx_out);

  // K3: r = q @ dec_w.T + dec_b   (M=512, N=4096, K=2048)
  gemm_nt_bias<<<dim3(BATCH / 64, HID / 64), 256, 0, stream>>>(
      q_out, dec_w, dec_b, r_out, BATCH, HID, NCD);
}